// Round 1
// baseline (180.695 us; speedup 1.0000x reference)
//
#include <hip/hip_runtime.h>

#define BB 8
#define CH 256
#define HH 96
#define WW 192
#define HW (HH*WW)            // 18432
#define ND 25
#define TH 32
#define TW 64
#define S2H 40                // TH + 8 halo
#define S2W 72                // TW + 8 halo
#define S2SLOTS (S2H*S2W/4)   // 720 float4 slots
#define NTHR 512
#define OUTSZ (BB*ND*HH*WW)   // 3686400

// Partial correlation: each block owns a 32x64 spatial tile of one batch image
// and a contiguous group of cCount channels (blockIdx.y). in2 halo tile staged
// per-channel in double-buffered LDS; in1 read straight to regs (no reuse).
__global__ __launch_bounds__(NTHR, 2)
void corr_partial(const float* __restrict__ in1, const float* __restrict__ in2,
                  float* __restrict__ part, int cCount) {
  __shared__ float s2[2][S2H*S2W];

  const int tile = blockIdx.x;
  const int b    = tile / 9;
  const int rem  = tile - b*9;
  const int h0   = (rem / 3) * TH;
  const int w0   = (rem % 3) * TW;
  const int t    = threadIdx.x;
  const int r    = t >> 4;            // 0..31 tile row
  const int c0   = (t & 15) << 2;     // 0..60 tile col (quad)

  const int cBegin = blockIdx.y * cCount;

  const size_t bplane = (size_t)b * CH * HW;
  const float* in1b = in1 + bplane;
  const float* in2b = in2 + bplane;

  // Staging slot 0 (all threads): slot = t -> (row, col4) of the 40x72 tile.
  const int s0row = t / 18, s0c4 = t - (t/18)*18;
  const int g0r = h0 + s0row - 4, g0c = w0 + (s0c4 << 2) - 4;
  const bool v0 = ((unsigned)g0r < HH) & ((unsigned)g0c <= (unsigned)(WW-4));
  const float* src0 = in2b + (size_t)cBegin*HW + (v0 ? (g0r*WW + g0c) : 0);
  const int lofs0 = s0row*S2W + (s0c4 << 2);

  // Staging slot 1 (threads 0..207): slot = t + 512.
  const int t1 = t + NTHR;
  const bool has1 = t1 < S2SLOTS;
  const int s1row = t1 / 18, s1c4 = t1 - (t1/18)*18;
  const int g1r = h0 + s1row - 4, g1c = w0 + (s1c4 << 2) - 4;
  const bool v1 = has1 & ((unsigned)g1r < HH) & ((unsigned)g1c <= (unsigned)(WW-4));
  const float* src1 = in2b + (size_t)cBegin*HW + (v1 ? (g1r*WW + g1c) : 0);
  const int lofs1 = has1 ? (s1row*S2W + (s1c4 << 2)) : lofs0;

  const float* p1 = in1b + (size_t)cBegin*HW + (h0 + r)*WW + (w0 + c0);

  float4 acc[ND];
  #pragma unroll
  for (int d = 0; d < ND; ++d) acc[d] = make_float4(0.f, 0.f, 0.f, 0.f);
  const float4 z4 = make_float4(0.f, 0.f, 0.f, 0.f);

  // Prologue: stage channel cBegin into buffer 0.
  {
    float4 x0 = v0 ? *(const float4*)src0 : z4;
    *(float4*)&s2[0][lofs0] = x0;
    if (has1) {
      float4 x1 = v1 ? *(const float4*)src1 : z4;
      *(float4*)&s2[0][lofs1] = x1;
    }
  }
  float4 a = *(const float4*)p1;
  __syncthreads();

  for (int cc = 0; cc < cCount; ++cc) {
    const int cur = cc & 1;
    float4 sv0 = z4, sv1 = z4, an = z4;
    const bool more = (cc + 1) < cCount;
    // 1) issue next channel's global loads early (latency hides under compute)
    if (more) {
      const size_t adv = (size_t)(cc + 1) * HW;
      if (v0) sv0 = *(const float4*)(src0 + adv);
      if (v1) sv1 = *(const float4*)(src1 + adv);
      an = *(const float4*)(p1 + adv);
    }
    // 2) compute on current LDS buffer
    const float* sbase = &s2[cur][0];
    #pragma unroll
    for (int dyi = 0; dyi < 5; ++dyi) {
      const float* rowp = sbase + (r + 2*dyi)*S2W + c0;
      float wv[12];
      *(float4*)&wv[0] = *(const float4*)(rowp);
      *(float4*)&wv[4] = *(const float4*)(rowp + 4);
      *(float4*)&wv[8] = *(const float4*)(rowp + 8);
      #pragma unroll
      for (int dxi = 0; dxi < 5; ++dxi) {
        float4& A = acc[dyi*5 + dxi];
        A.x = fmaf(a.x, wv[0 + 2*dxi], A.x);
        A.y = fmaf(a.y, wv[1 + 2*dxi], A.y);
        A.z = fmaf(a.z, wv[2 + 2*dxi], A.z);
        A.w = fmaf(a.w, wv[3 + 2*dxi], A.w);
      }
    }
    // 3) late write of staged regs into the other buffer
    if (more) {
      float* dbase = &s2[cur ^ 1][0];
      *(float4*)(dbase + lofs0) = sv0;
      if (has1) *(float4*)(dbase + lofs1) = sv1;
      a = an;
    }
    __syncthreads();
  }

  // Epilogue: scaled partial write, [g][b][d][h][w], coalesced float4.
  const float scale = 1.0f / CH;
  float* pout = part + (size_t)blockIdx.y * OUTSZ
              + ((size_t)b*ND*HH + (h0 + r))*WW + (w0 + c0);
  #pragma unroll
  for (int d = 0; d < ND; ++d) {
    float4 v;
    v.x = acc[d].x * scale; v.y = acc[d].y * scale;
    v.z = acc[d].z * scale; v.w = acc[d].w * scale;
    *(float4*)(pout + (size_t)d*HW) = v;
  }
}

__global__ void corr_reduce(const float* __restrict__ part,
                            float* __restrict__ out, int G) {
  const int n4 = OUTSZ / 4;
  int i = blockIdx.x * 256 + threadIdx.x;
  if (i >= n4) return;
  const float4* p = (const float4*)part;
  float4 s = p[i];
  for (int g = 1; g < G; ++g) {
    float4 v = p[(size_t)g * n4 + i];
    s.x += v.x; s.y += v.y; s.z += v.z; s.w += v.w;
  }
  ((float4*)out)[i] = s;
}

extern "C" void kernel_launch(void* const* d_in, const int* in_sizes, int n_in,
                              void* d_out, int out_size, void* d_ws, size_t ws_size,
                              hipStream_t stream) {
  const float* in1 = (const float*)d_in[0];
  const float* in2 = (const float*)d_in[1];
  float* out = (float*)d_out;

  int G = 4;  // channel groups; fall back if workspace is small
  while (G > 1 && ws_size < (size_t)G * OUTSZ * sizeof(float)) G >>= 1;
  float* part = (G == 1) ? out : (float*)d_ws;

  dim3 grid(BB * 9, G);  // 72 spatial tiles x G channel groups
  corr_partial<<<grid, NTHR, 0, stream>>>(in1, in2, part, CH / G);
  if (G > 1) {
    corr_reduce<<<(OUTSZ/4 + 255)/256, 256, 0, stream>>>((const float*)d_ws, out, G);
  }
}

// Round 2
// 153.034 us; speedup vs baseline: 1.1808x; 1.1808x over previous
//
#include <hip/hip_runtime.h>

#define BB 8
#define CH 256
#define HH 96
#define WW 192
#define HW (HH*WW)            // 18432
#define ND 25
#define TH 16                 // tile rows per block
#define TW 64                 // tile cols per block
#define S2H 24                // TH + 8 halo
#define S2W 72                // TW + 8 halo
#define S2Q (S2H*S2W/4)       // 432 float4 slots per half-tile
#define NTHR 512
#define OUTSZ (BB*ND*HH*WW)   // 3686400

// Each block: 16x64 spatial tile, 2 half-groups of 256 threads.
// Half h processes channels [cBase + h*cPerHalf, +cPerHalf) with its own
// LDS double-buffered in2 halo tile; halves run independent pipelines
// lock-stepped by block barriers (identical iteration counts). Final
// cross-half reduce in LDS, then one partial write per output element.
__global__ __launch_bounds__(NTHR, 2)
void corr_partial(const float* __restrict__ in1, const float* __restrict__ in2,
                  float* __restrict__ part, int cPerHalf, int G) {
  __shared__ __align__(16) float smem[2][2][S2H*S2W];  // [half][buf][tile] 27.6 KB

  const int tile = blockIdx.x;
  const int b    = tile / 18;
  const int rem  = tile - b*18;
  const int h0   = (rem / 3) * TH;
  const int w0   = (rem % 3) * TW;
  const int t    = threadIdx.x;
  const int half = t >> 8;
  const int ti   = t & 255;
  const int r    = ti >> 4;           // 0..15 tile row
  const int c0   = (ti & 15) << 2;    // 0..60 tile col (quad)

  const int cBegin = blockIdx.y * (cPerHalf * 2) + half * cPerHalf;

  const size_t bplane = (size_t)b * CH * HW;
  const float* in1b = in1 + bplane;
  const float* in2b = in2 + bplane;

  // Staging slot 0 (all 256 threads of the half): slot = ti.
  const int s0row = ti / 18, s0q = ti - (ti/18)*18;
  const int g0r = h0 + s0row - 4, g0c = w0 + (s0q << 2) - 4;
  const bool v0 = ((unsigned)g0r < HH) & ((unsigned)g0c <= (unsigned)(WW-4));
  const float* src0 = in2b + (size_t)cBegin*HW + (v0 ? (g0r*WW + g0c) : 0);
  const int lofs0 = s0row*S2W + (s0q << 2);

  // Staging slot 1 (ti < 176): slot = ti + 256.
  const int t1 = ti + 256;
  const bool has1 = t1 < S2Q;
  const int s1row = t1 / 18, s1q = t1 - (t1/18)*18;
  const int g1r = h0 + s1row - 4, g1c = w0 + (s1q << 2) - 4;
  const bool v1 = has1 & ((unsigned)g1r < HH) & ((unsigned)g1c <= (unsigned)(WW-4));
  const float* src1 = in2b + (size_t)cBegin*HW + (v1 ? (g1r*WW + g1c) : 0);
  const int lofs1 = has1 ? (s1row*S2W + (s1q << 2)) : lofs0;

  const float* p1 = in1b + (size_t)cBegin*HW + (h0 + r)*WW + (w0 + c0);

  float4 acc[ND];
  #pragma unroll
  for (int d = 0; d < ND; ++d) acc[d] = make_float4(0.f, 0.f, 0.f, 0.f);
  const float4 z4 = make_float4(0.f, 0.f, 0.f, 0.f);

  // Prologue: stage first channel of this half into buffer 0.
  {
    float4 x0 = v0 ? *(const float4*)src0 : z4;
    *(float4*)&smem[half][0][lofs0] = x0;
    if (has1) {
      float4 x1 = v1 ? *(const float4*)src1 : z4;
      *(float4*)&smem[half][0][lofs1] = x1;
    }
  }
  float4 a = *(const float4*)p1;
  __syncthreads();

  for (int cc = 0; cc < cPerHalf; ++cc) {
    const int cur = cc & 1;
    float4 sv0 = z4, sv1 = z4, an = z4;
    const bool more = (cc + 1) < cPerHalf;
    // 1) issue next channel's global loads early
    if (more) {
      const size_t adv = (size_t)(cc + 1) * HW;
      if (v0) sv0 = *(const float4*)(src0 + adv);
      if (v1) sv1 = *(const float4*)(src1 + adv);
      an = *(const float4*)(p1 + adv);
    }
    // 2) compute on this half's current LDS buffer
    const float* sbase = &smem[half][cur][0];
    #pragma unroll
    for (int dyi = 0; dyi < 5; ++dyi) {
      const float* rowp = sbase + (r + 2*dyi)*S2W + c0;
      float wv[12];
      *(float4*)&wv[0] = *(const float4*)(rowp);
      *(float4*)&wv[4] = *(const float4*)(rowp + 4);
      *(float4*)&wv[8] = *(const float4*)(rowp + 8);
      #pragma unroll
      for (int dxi = 0; dxi < 5; ++dxi) {
        float4& A = acc[dyi*5 + dxi];
        A.x = fmaf(a.x, wv[0 + 2*dxi], A.x);
        A.y = fmaf(a.y, wv[1 + 2*dxi], A.y);
        A.z = fmaf(a.z, wv[2 + 2*dxi], A.z);
        A.w = fmaf(a.w, wv[3 + 2*dxi], A.w);
      }
    }
    // 3) late write of staged regs into the other buffer
    if (more) {
      float* dbase = &smem[half][cur ^ 1][0];
      *(float4*)(dbase + lofs0) = sv0;
      if (has1) *(float4*)(dbase + lofs1) = sv1;
      a = an;
    }
    __syncthreads();
  }

  // Cross-half reduce via LDS (reuse channel buffers), 5 chunks x 5 disps.
  const float scale = 1.0f / CH;
  float4* red = (float4*)&smem[0][0][0];   // need 5*256 float4 = 20 KB <= 27.6
  float* pout = part + (size_t)blockIdx.y * OUTSZ
              + ((size_t)b*ND*HH + (h0 + r))*WW + (w0 + c0);
  for (int ch5 = 0; ch5 < 5; ++ch5) {
    if (half == 1) {
      #pragma unroll
      for (int dd = 0; dd < 5; ++dd) red[dd*256 + ti] = acc[ch5*5 + dd];
    }
    __syncthreads();
    if (half == 0) {
      #pragma unroll
      for (int dd = 0; dd < 5; ++dd) {
        const int d = ch5*5 + dd;
        float4 v = red[dd*256 + ti];
        float4 o;
        o.x = (acc[d].x + v.x) * scale;
        o.y = (acc[d].y + v.y) * scale;
        o.z = (acc[d].z + v.z) * scale;
        o.w = (acc[d].w + v.w) * scale;
        *(float4*)(pout + (size_t)d*HW) = o;
      }
    }
    __syncthreads();
  }
}

__global__ void corr_reduce(const float* __restrict__ part,
                            float* __restrict__ out, int G) {
  const int n4 = OUTSZ / 4;
  int i = blockIdx.x * 256 + threadIdx.x;
  if (i >= n4) return;
  const float4* p = (const float4*)part;
  float4 s = p[i];
  for (int g = 1; g < G; ++g) {
    float4 v = p[(size_t)g * n4 + i];
    s.x += v.x; s.y += v.y; s.z += v.z; s.w += v.w;
  }
  ((float4*)out)[i] = s;
}

extern "C" void kernel_launch(void* const* d_in, const int* in_sizes, int n_in,
                              void* d_out, int out_size, void* d_ws, size_t ws_size,
                              hipStream_t stream) {
  const float* in1 = (const float*)d_in[0];
  const float* in2 = (const float*)d_in[1];
  float* out = (float*)d_out;

  int G = 4;  // outer channel groups (x2 in-block halves = 8-way channel split)
  while (G > 1 && ws_size < (size_t)G * OUTSZ * sizeof(float)) G >>= 1;
  float* part = (G == 1) ? out : (float*)d_ws;

  dim3 grid(BB * 18, G);  // 144 spatial tiles x G channel groups
  corr_partial<<<grid, NTHR, 0, stream>>>(in1, in2, part, CH / (G * 2), G);
  if (G > 1) {
    corr_reduce<<<(OUTSZ/4 + 255)/256, 256, 0, stream>>>((const float*)d_ws, out, G);
  }
}